// Round 10
// baseline (604.850 us; speedup 1.0000x reference)
//
#include <hip/hip_runtime.h>
#include <math.h>

#define TT 20
#define HH 20

typedef float f32x4 __attribute__((ext_vector_type(4)));
typedef short bf16x8 __attribute__((ext_vector_type(8)));
typedef unsigned uint4v __attribute__((ext_vector_type(4)));

__device__ __forceinline__ short f2bf(float f) {
    unsigned u = __float_as_uint(f);
    unsigned r = (u + 0x7fffu + ((u >> 16) & 1u)) >> 16;
    return (short)r;
}

// packed f32x2 -> bf16x2 (RTNE), a -> low half, b -> high half
__device__ __forceinline__ unsigned pk_bf16(float a, float b) {
    unsigned r;
    asm("v_cvt_pk_bf16_f32 %0, %1, %2" : "=v"(r) : "v"(a), "v"(b));
    return r;
}

// VALU-pipe exp2: rint range-reduce to r in [-0.5,0.5], deg-4 Horner, ldexp.
// ~9 VALU inst, rel err ~4e-5 (100x below bf16 state noise). Runs on the
// full-rate ALU, NOT the quarter-rate trans unit -> frees trans-pipe slots.
__device__ __forceinline__ float poly_exp2(float v) {
    const float fl = __builtin_rintf(v);
    const float r  = v - fl;
    const int   ie = (int)fl;
    float p = fmaf(r, 0.0096181291f, 0.0555041087f);
    p = fmaf(r, p, 0.2402265070f);
    p = fmaf(r, p, 0.6931471806f);
    p = fmaf(r, p, 1.0f);
    return ldexpf(p, ie);
}

// Build B fragment (pure bf16) from lane-local state.
// Lane (g = lane>>4, n = lane&15): B[k = 8g+e][col]; e<5 -> h[unit 4e+g],
// e=7 -> x (g==0) / 1.0 (g==1) / 0; e=5,6 pad. 4 cvt_pk + 1 fma per frag.
__device__ __forceinline__ void build_B(const float (&hn)[5][4], const float (&xv)[4],
                                        float xm, float om, bf16x8 (&Bhi)[4])
{
    #pragma unroll
    for (int b = 0; b < 4; ++b) {
        const float s7 = fmaf(xm, xv[b], om);
        uint4v uh;
        uh[0] = pk_bf16(hn[0][b], hn[1][b]);
        uh[1] = pk_bf16(hn[2][b], hn[3][b]);
        uh[2] = pk_bf16(hn[4][b], 0.0f);
        uh[3] = pk_bf16(0.0f, s7);
        Bhi[b] = __builtin_bit_cast(bf16x8, uh);
    }
}

// Per-unit nonlinearity (i,f,g,o in acc regs 0..3). i/f/o pre-scaled by
// -log2e, g by +2log2e at A-build time. Merged-rcp forms; exp work split
// across pipes: ei/ef/eo on VALU poly, eg/ec + both rcps on trans unit.
__device__ __forceinline__ void nonlin(const f32x4 a, float& cst, float& hout,
                                       const float TLOG2E)
{
    const float ei = poly_exp2(a[0]);
    const float ef = poly_exp2(a[1]);
    const float eg = __builtin_amdgcn_exp2f(a[2]);
    const float eo = poly_exp2(a[3]);
    const float pi = 1.0f + ei, pf = 1.0f + ef;
    const float pg = 1.0f + eg, po = 1.0f + eo;
    const float pig = pi * pg;
    const float r3  = __builtin_amdgcn_rcpf(pig * pf);
    const float cn  = fmaf(cst, pig, (eg - 1.0f) * pf) * r3;
    cst = cn;
    const float ec = __builtin_amdgcn_exp2f(TLOG2E * cn);
    const float pc = 1.0f + ec;
    hout = (ec - 1.0f) * __builtin_amdgcn_rcpf(po * pc);
}

// 256 threads = 4 independent waves. One wave = 64 coords, all 20 steps.
// Pure-bf16 MFMA path: weights ONCE in VGPR A-fragments, 24 MFMAs/step.
__global__ __launch_bounds__(256)
void coord_lstm_mfma(const float* __restrict__ grads,
                     const float* __restrict__ w_ih,
                     const float* __restrict__ w_hh,
                     const float* __restrict__ b_ih,
                     const float* __restrict__ b_hh,
                     const float* __restrict__ w_fc,
                     const float* __restrict__ b_fc,
                     float* __restrict__ out,
                     int N)
{
    const int lane = threadIdx.x & 63;
    const int g = lane >> 4;
    const int n = lane & 15;
    const long long base = ((long long)blockIdx.x * 4 + (threadIdx.x >> 6)) * 64;
    if (base >= N) return;

    const float LOG2E  = 1.4426950408889634f;
    const float TLOG2E = 2.8853900817779268f;
    const float xm = (g == 0) ? 1.0f : 0.0f;
    const float om = (g == 1) ? 1.0f : 0.0f;

    // ---- A fragments (bf16, RTNE), built once. Tiles 0..4: row r=16*tA+n ->
    // unit r>>2, gate r&3 (0=i 1=f 2=g 3=o), source row gate*HH+unit,
    // pre-scaled. Tile 5: w_fc / b_fc, unscaled.
    bf16x8 Ahi[6];
    #pragma unroll
    for (int tA = 0; tA < 6; ++tA) {
        bf16x8 ah;
        #pragma unroll
        for (int e = 0; e < 8; ++e) {
            float v = 0.0f;
            if (tA < 5) {
                const int r = 16 * tA + n;
                const int u_r = r >> 2;
                const int gate = r & 3;
                const float scale = (gate == 2) ? TLOG2E : -LOG2E;
                const int row_w = gate * HH + u_r;
                if (e < 5)       v = scale * w_hh[row_w * HH + (4 * e + g)];
                else if (e == 7) v = (g == 0) ? scale * w_ih[row_w]
                                   : (g == 1) ? scale * (b_ih[row_w] + b_hh[row_w]) : 0.0f;
            } else {
                if (e < 5)       v = (n == 0) ? w_fc[4 * e + g] : 0.0f;
                else if (e == 7) v = (g == 1 && n == 0) ? b_fc[0] : 0.0f;
            }
            ah[e] = f2bf(v);
        }
        Ahi[tA] = ah;
    }

    const f32x4 zero4 = {0.0f, 0.0f, 0.0f, 0.0f};

    // clamped coordinates + store guards, then everything incremental
    long long cc[4]; bool wr[4];
    #pragma unroll
    for (int b = 0; b < 4; ++b) {
        long long c0 = base + 16 * b + n;
        wr[b] = (c0 < N);
        cc[b] = wr[b] ? c0 : (long long)(N - 1);
    }
    const float* gp0 = grads + cc[0];
    const float* gp1 = grads + cc[1];
    const float* gp2 = grads + cc[2];
    const float* gp3 = grads + cc[3];
    float* op0 = out + cc[0];
    float* op1 = out + cc[1];
    float* op2 = out + cc[2];
    float* op3 = out + cc[3];

    float c[5][4], hn[5][4];
    #pragma unroll
    for (int t5 = 0; t5 < 5; ++t5)
        #pragma unroll
        for (int b = 0; b < 4; ++b) { c[t5][b] = 0.0f; hn[t5][b] = 0.0f; }

    float xv[4];
    xv[0] = *gp0; gp0 += N;
    xv[1] = *gp1; gp1 += N;
    xv[2] = *gp2; gp2 += N;
    xv[3] = *gp3; gp3 += N;        // now point at t=1

    bf16x8 Bhi[4];
    build_B(hn, xv, xm, om, Bhi);  // [h(-1)=0 ; x(0); 1]

    #pragma unroll 1
    for (int t = 0; t < TT; ++t) {
        // prefetch x(t+1); last iter feeds 0 (pad slot, A column is zero)
        float xn[4];
        if (t < TT - 1) {
            xn[0] = *gp0; gp0 += N;
            xn[1] = *gp1; gp1 += N;
            xn[2] = *gp2; gp2 += N;
            xn[3] = *gp3; gp3 += N;
        } else {
            xn[0] = 0.0f; xn[1] = 0.0f; xn[2] = 0.0f; xn[3] = 0.0f;
        }

        // per tile: 4 MFMAs then lane-local nonlinearity (i,f,g,o in regs 0..3)
        #pragma unroll
        for (int tile = 0; tile < 5; ++tile) {
            f32x4 acc[4];
            #pragma unroll
            for (int b = 0; b < 4; ++b)
                acc[b] = __builtin_amdgcn_mfma_f32_16x16x32_bf16(Ahi[tile], Bhi[b], zero4, 0, 0, 0);
            #pragma unroll
            for (int b = 0; b < 4; ++b)
                nonlin(acc[b], c[tile][b], hn[tile][b], TLOG2E);
        }

        // B_new = [h(t); x(t+1); 1]
        build_B(hn, xn, xm, om, Bhi);

        // out(t) = w_fc . h(t) + b_fc   (tile 5 -> lanes g==0, reg 0)
        f32x4 ov[4];
        #pragma unroll
        for (int b = 0; b < 4; ++b)
            ov[b] = __builtin_amdgcn_mfma_f32_16x16x32_bf16(Ahi[5], Bhi[b], zero4, 0, 0, 0);

        if (g == 0) {
            if (wr[0]) *op0 = ov[0][0];
            if (wr[1]) *op1 = ov[1][0];
            if (wr[2]) *op2 = ov[2][0];
            if (wr[3]) *op3 = ov[3][0];
        }
        op0 += N; op1 += N; op2 += N; op3 += N;
    }
}

extern "C" void kernel_launch(void* const* d_in, const int* in_sizes, int n_in,
                              void* d_out, int out_size, void* d_ws, size_t ws_size,
                              hipStream_t stream) {
    const float* grads = (const float*)d_in[0];
    const float* w_ih  = (const float*)d_in[1];
    const float* w_hh  = (const float*)d_in[2];
    const float* b_ih  = (const float*)d_in[3];
    const float* b_hh  = (const float*)d_in[4];
    const float* w_fc  = (const float*)d_in[5];
    const float* b_fc  = (const float*)d_in[6];
    float* out = (float*)d_out;

    const int N = in_sizes[0] / TT;            // grads is (T, N)
    const long long waves = ((long long)N + 63) / 64;
    const int blocks = (int)((waves + 3) / 4); // 4 waves per 256-thread block
    coord_lstm_mfma<<<blocks, 256, 0, stream>>>(grads, w_ih, w_hh, b_ih, b_hh,
                                                w_fc, b_fc, out, N);
}

// Round 11
// 372.356 us; speedup vs baseline: 1.6244x; 1.6244x over previous
//
#include <hip/hip_runtime.h>

#define TT 20
#define HH 20

typedef float f32x4 __attribute__((ext_vector_type(4)));
typedef short bf16x8 __attribute__((ext_vector_type(8)));
typedef unsigned uint4v __attribute__((ext_vector_type(4)));

__device__ __forceinline__ short f2bf(float f) {
    unsigned u = __float_as_uint(f);
    unsigned r = (u + 0x7fffu + ((u >> 16) & 1u)) >> 16;
    return (short)r;
}

// packed f32x2 -> bf16x2 (RTNE), a -> low half, b -> high half
__device__ __forceinline__ unsigned pk_bf16(float a, float b) {
    unsigned r;
    asm("v_cvt_pk_bf16_f32 %0, %1, %2" : "=v"(r) : "v"(a), "v"(b));
    return r;
}

// Build B fragment (pure bf16) from lane-local state.
// Lane (g = lane>>4, n = lane&15): B[k = 8g+e][col]; e<5 -> h[unit 4e+g],
// e=7 -> x (g==0) / 1.0 (g==1) / 0; e=5,6 pad. 4 cvt_pk + 1 fma per frag.
__device__ __forceinline__ void build_B(const float (&hn)[5][4], const float (&xv)[4],
                                        float xm, float om, bf16x8 (&Bhi)[4])
{
    #pragma unroll
    for (int b = 0; b < 4; ++b) {
        const float s7 = fmaf(xm, xv[b], om);
        uint4v uh;
        uh[0] = pk_bf16(hn[0][b], hn[1][b]);
        uh[1] = pk_bf16(hn[2][b], hn[3][b]);
        uh[2] = pk_bf16(hn[4][b], 0.0f);
        uh[3] = pk_bf16(0.0f, s7);
        Bhi[b] = __builtin_bit_cast(bf16x8, uh);
    }
}

// Per-unit nonlinearity on one MFMA accumulator (i,f,g,o in regs 0..3).
// i/f/o pre-scaled by -log2e, g by +2log2e at A-build time, so acc feeds
// v_exp_f32 directly. Merged-rcp forms: 5 exp + 2 rcp per unit — the
// trans-op minimum for exact-exp LSTM (R10 proved trans<->VALU swaps lose:
// shared issue port, v_exp=16 cyc < 10-inst poly).
__device__ __forceinline__ void nonlin(const f32x4 a, float& cst, float& hout,
                                       const float TLOG2E)
{
    const float ei = __builtin_amdgcn_exp2f(a[0]);
    const float ef = __builtin_amdgcn_exp2f(a[1]);
    const float eg = __builtin_amdgcn_exp2f(a[2]);
    const float eo = __builtin_amdgcn_exp2f(a[3]);
    const float pi = 1.0f + ei, pf = 1.0f + ef;
    const float pg = 1.0f + eg, po = 1.0f + eo;
    const float pig = pi * pg;
    const float r3  = __builtin_amdgcn_rcpf(pig * pf);
    const float cn  = fmaf(cst, pig, (eg - 1.0f) * pf) * r3;
    cst = cn;
    const float ec = __builtin_amdgcn_exp2f(TLOG2E * cn);
    const float pc = 1.0f + ec;
    hout = (ec - 1.0f) * __builtin_amdgcn_rcpf(po * pc);
}

// 256 threads = 4 independent waves. One wave = 64 coords, all 20 steps.
// Pure-bf16 MFMA path: weights ONCE in VGPR A-fragments, 24 MFMAs/step.
// __launch_bounds__(256,3): 170-reg ceiling >= ~125 actual need (84 VGPR +
// ~40 acc/frag AGPR in the unified file) -> guarantees 3 waves/SIMD to fill
// the ~600-cyc/step serial-spine stall R9 showed at 2.5 waves. NOT like
// R2/R3's disasters (need >> cap there); spill signature = FETCH balloon.
__global__ __launch_bounds__(256, 3)
void coord_lstm_mfma(const float* __restrict__ grads,
                     const float* __restrict__ w_ih,
                     const float* __restrict__ w_hh,
                     const float* __restrict__ b_ih,
                     const float* __restrict__ b_hh,
                     const float* __restrict__ w_fc,
                     const float* __restrict__ b_fc,
                     float* __restrict__ out,
                     int N)
{
    const int lane = threadIdx.x & 63;
    const int g = lane >> 4;
    const int n = lane & 15;
    const long long base = ((long long)blockIdx.x * 4 + (threadIdx.x >> 6)) * 64;
    if (base >= N) return;

    const float LOG2E  = 1.4426950408889634f;
    const float TLOG2E = 2.8853900817779268f;
    const float xm = (g == 0) ? 1.0f : 0.0f;
    const float om = (g == 1) ? 1.0f : 0.0f;

    // ---- A fragments (bf16, RTNE), built once. Tiles 0..4: row r=16*tA+n ->
    // unit r>>2, gate r&3 (0=i 1=f 2=g 3=o), source row gate*HH+unit,
    // pre-scaled. Tile 5: w_fc / b_fc, unscaled.
    bf16x8 Ahi[6];
    #pragma unroll
    for (int tA = 0; tA < 6; ++tA) {
        bf16x8 ah;
        #pragma unroll
        for (int e = 0; e < 8; ++e) {
            float v = 0.0f;
            if (tA < 5) {
                const int r = 16 * tA + n;
                const int u_r = r >> 2;
                const int gate = r & 3;
                const float scale = (gate == 2) ? TLOG2E : -LOG2E;
                const int row_w = gate * HH + u_r;
                if (e < 5)       v = scale * w_hh[row_w * HH + (4 * e + g)];
                else if (e == 7) v = (g == 0) ? scale * w_ih[row_w]
                                   : (g == 1) ? scale * (b_ih[row_w] + b_hh[row_w]) : 0.0f;
            } else {
                if (e < 5)       v = (n == 0) ? w_fc[4 * e + g] : 0.0f;
                else if (e == 7) v = (g == 1 && n == 0) ? b_fc[0] : 0.0f;
            }
            ah[e] = f2bf(v);
        }
        Ahi[tA] = ah;
    }

    const f32x4 zero4 = {0.0f, 0.0f, 0.0f, 0.0f};

    // clamped coordinates + store guards, then everything incremental
    long long cc[4]; bool wr[4];
    #pragma unroll
    for (int b = 0; b < 4; ++b) {
        long long c0 = base + 16 * b + n;
        wr[b] = (c0 < N);
        cc[b] = wr[b] ? c0 : (long long)(N - 1);
    }
    const float* gp0 = grads + cc[0];
    const float* gp1 = grads + cc[1];
    const float* gp2 = grads + cc[2];
    const float* gp3 = grads + cc[3];
    float* op0 = out + cc[0];
    float* op1 = out + cc[1];
    float* op2 = out + cc[2];
    float* op3 = out + cc[3];

    float c[5][4], hn[5][4];
    #pragma unroll
    for (int t5 = 0; t5 < 5; ++t5)
        #pragma unroll
        for (int b = 0; b < 4; ++b) { c[t5][b] = 0.0f; hn[t5][b] = 0.0f; }

    float xv[4];
    xv[0] = *gp0; gp0 += N;
    xv[1] = *gp1; gp1 += N;
    xv[2] = *gp2; gp2 += N;
    xv[3] = *gp3; gp3 += N;        // now point at t=1

    bf16x8 Bhi[4];
    build_B(hn, xv, xm, om, Bhi);  // [h(-1)=0 ; x(0); 1]

    #pragma unroll 1
    for (int t = 0; t < TT; ++t) {
        // prefetch x(t+1); last iter feeds 0 (pad slot, A column is zero)
        float xn[4];
        if (t < TT - 1) {
            xn[0] = *gp0; gp0 += N;
            xn[1] = *gp1; gp1 += N;
            xn[2] = *gp2; gp2 += N;
            xn[3] = *gp3; gp3 += N;
        } else {
            xn[0] = 0.0f; xn[1] = 0.0f; xn[2] = 0.0f; xn[3] = 0.0f;
        }

        // per tile: 4 MFMAs then lane-local nonlinearity (i,f,g,o in regs 0..3)
        #pragma unroll
        for (int tile = 0; tile < 5; ++tile) {
            f32x4 acc[4];
            #pragma unroll
            for (int b = 0; b < 4; ++b)
                acc[b] = __builtin_amdgcn_mfma_f32_16x16x32_bf16(Ahi[tile], Bhi[b], zero4, 0, 0, 0);
            #pragma unroll
            for (int b = 0; b < 4; ++b)
                nonlin(acc[b], c[tile][b], hn[tile][b], TLOG2E);
        }

        // B_new = [h(t); x(t+1); 1]
        build_B(hn, xn, xm, om, Bhi);

        // out(t) = w_fc . h(t) + b_fc   (tile 5 -> lanes g==0, reg 0)
        f32x4 ov[4];
        #pragma unroll
        for (int b = 0; b < 4; ++b)
            ov[b] = __builtin_amdgcn_mfma_f32_16x16x32_bf16(Ahi[5], Bhi[b], zero4, 0, 0, 0);

        if (g == 0) {
            if (wr[0]) *op0 = ov[0][0];
            if (wr[1]) *op1 = ov[1][0];
            if (wr[2]) *op2 = ov[2][0];
            if (wr[3]) *op3 = ov[3][0];
        }
        op0 += N; op1 += N; op2 += N; op3 += N;
    }
}

extern "C" void kernel_launch(void* const* d_in, const int* in_sizes, int n_in,
                              void* d_out, int out_size, void* d_ws, size_t ws_size,
                              hipStream_t stream) {
    const float* grads = (const float*)d_in[0];
    const float* w_ih  = (const float*)d_in[1];
    const float* w_hh  = (const float*)d_in[2];
    const float* b_ih  = (const float*)d_in[3];
    const float* b_hh  = (const float*)d_in[4];
    const float* w_fc  = (const float*)d_in[5];
    const float* b_fc  = (const float*)d_in[6];
    float* out = (float*)d_out;

    const int N = in_sizes[0] / TT;            // grads is (T, N)
    const long long waves = ((long long)N + 63) / 64;
    const int blocks = (int)((waves + 3) / 4); // 4 waves per 256-thread block
    coord_lstm_mfma<<<blocks, 256, 0, stream>>>(grads, w_ih, w_hh, b_ih, b_hh,
                                                w_fc, b_fc, out, N);
}

// Round 12
// 361.609 us; speedup vs baseline: 1.6727x; 1.0297x over previous
//
#include <hip/hip_runtime.h>

#define TT 20
#define HH 20

typedef float f32x4 __attribute__((ext_vector_type(4)));
typedef float f32x2 __attribute__((ext_vector_type(2)));
typedef short bf16x8 __attribute__((ext_vector_type(8)));
typedef unsigned uint4v __attribute__((ext_vector_type(4)));

__device__ __forceinline__ short f2bf(float f) {
    unsigned u = __float_as_uint(f);
    unsigned r = (u + 0x7fffu + ((u >> 16) & 1u)) >> 16;
    return (short)r;
}

// packed f32x2 -> bf16x2 (RTNE), a -> low half, b -> high half
__device__ __forceinline__ unsigned pk_bf16(float a, float b) {
    unsigned r;
    asm("v_cvt_pk_bf16_f32 %0, %1, %2" : "=v"(r) : "v"(a), "v"(b));
    return r;
}

// One B fragment (pure bf16) from 5 lane-local h values + the e7 slot.
// Lane (g,n): B[k=8g+e][col]; e<5 -> h[unit 4e+g], e=7 -> x/1/0, e=5,6 pad.
__device__ __forceinline__ bf16x8 build_frag(const float (&h)[5], float s7) {
    uint4v uh;
    uh[0] = pk_bf16(h[0], h[1]);
    uh[1] = pk_bf16(h[2], h[3]);
    uh[2] = pk_bf16(h[4], 0.0f);
    uh[3] = pk_bf16(0.0f, s7);
    return __builtin_bit_cast(bf16x8, uh);
}

#define TLOG2E_C 2.8853900817779268f

// Per-unit nonlinearity. acc = (i',f',g',o'): i/f/o pre-scaled by -log2e,
// g by +2log2e at A-build. c-state is stored PRE-SCALED by 2log2e (cS), so
// the tanh(c) exp needs no argument mul. (i,f)/(g,o) adds pair into
// v_pk_add_f32 (contiguous acc regs). 5 exp + 2 rcp per unit (trans floor).
__device__ __forceinline__ void nonlin(const f32x4 a, float& cS, float& hout) {
    f32x2 e_if, e_go;
    e_if.x = __builtin_amdgcn_exp2f(a[0]);
    e_if.y = __builtin_amdgcn_exp2f(a[1]);
    e_go.x = __builtin_amdgcn_exp2f(a[2]);
    e_go.y = __builtin_amdgcn_exp2f(a[3]);
    const f32x2 one2 = {1.0f, 1.0f};
    const f32x2 p_if = e_if + one2;          // v_pk_add_f32: (1+ei, 1+ef)
    const f32x2 p_go = e_go + one2;          // (1+eg, 1+eo)
    const float pig = p_if.x * p_go.x;
    const float r3  = __builtin_amdgcn_rcpf(pig * p_if.y);
    const float tn  = fmaf(e_go.x, TLOG2E_C, -TLOG2E_C) * p_if.y;  // 2log2e*(eg-1)*pf
    const float cnS = fmaf(cS, pig, tn) * r3;                      // = 2log2e * c_new
    cS = cnS;
    const float ec = __builtin_amdgcn_exp2f(cnS);
    const float pc = 1.0f + ec;
    hout = (ec - 1.0f) * __builtin_amdgcn_rcpf(p_go.y * pc);
}

// 256 threads = 4 independent waves; one wave = 64 coords, all 20 steps.
// Weights once in VGPR A-fragments; 24 MFMAs/step. Per-b restructure keeps
// live state minimal (hn 5 regs, acc 20) so (256,4) fits the 512-reg/SIMD
// pool at 4 waves -> fill the ~13% issue stall R11 left. ALIGNED path
// (N%64==0, true for the harness) uses one load + one store pointer with
// immediate offsets, no clamps or guards.
template <bool ALIGNED>
__global__ __launch_bounds__(256, 4)
void coord_lstm_mfma(const float* __restrict__ grads,
                     const float* __restrict__ w_ih,
                     const float* __restrict__ w_hh,
                     const float* __restrict__ b_ih,
                     const float* __restrict__ b_hh,
                     const float* __restrict__ w_fc,
                     const float* __restrict__ b_fc,
                     float* __restrict__ out,
                     int N)
{
    const int lane = threadIdx.x & 63;
    const int g = lane >> 4;
    const int n = lane & 15;
    const long long base = ((long long)blockIdx.x * 4 + (threadIdx.x >> 6)) * 64;
    if (base >= N) return;

    const float LOG2E  = 1.4426950408889634f;
    const float TLOG2E = TLOG2E_C;
    const float xm = (g == 0) ? 1.0f : 0.0f;
    const float om = (g == 1) ? 1.0f : 0.0f;

    // ---- A fragments (bf16 RTNE), built once. Tiles 0..4: row r=16*tA+n ->
    // unit r>>2, gate r&3 (0=i 1=f 2=g 3=o), source row gate*HH+unit,
    // pre-scaled (-log2e for i/f/o, +2log2e for g). Tile 5: w_fc/b_fc.
    bf16x8 Ahi[6];
    #pragma unroll
    for (int tA = 0; tA < 6; ++tA) {
        bf16x8 ah;
        #pragma unroll
        for (int e = 0; e < 8; ++e) {
            float v = 0.0f;
            if (tA < 5) {
                const int r = 16 * tA + n;
                const int u_r = r >> 2;
                const int gate = r & 3;
                const float scale = (gate == 2) ? TLOG2E : -LOG2E;
                const int row_w = gate * HH + u_r;
                if (e < 5)       v = scale * w_hh[row_w * HH + (4 * e + g)];
                else if (e == 7) v = (g == 0) ? scale * w_ih[row_w]
                                   : (g == 1) ? scale * (b_ih[row_w] + b_hh[row_w]) : 0.0f;
            } else {
                if (e < 5)       v = (n == 0) ? w_fc[4 * e + g] : 0.0f;
                else if (e == 7) v = (g == 1 && n == 0) ? b_fc[0] : 0.0f;
            }
            ah[e] = f2bf(v);
        }
        Ahi[tA] = ah;
    }

    const f32x4 zero4 = {0.0f, 0.0f, 0.0f, 0.0f};

    // addressing
    const float* gp;          // load ptr (ALIGNED: +16b imm offsets)
    float* op;
    long long cc[4]; bool wr[4];
    const float *gpc0, *gpc1, *gpc2, *gpc3;
    float *opc0, *opc1, *opc2, *opc3;
    if constexpr (ALIGNED) {
        gp = grads + base + n;
        op = out + base + n;
        (void)cc; (void)wr;
        gpc0 = gpc1 = gpc2 = gpc3 = nullptr;
        opc0 = opc1 = opc2 = opc3 = nullptr;
    } else {
        #pragma unroll
        for (int b = 0; b < 4; ++b) {
            long long c0 = base + 16 * b + n;
            wr[b] = (c0 < N);
            cc[b] = wr[b] ? c0 : (long long)(N - 1);
        }
        gpc0 = grads + cc[0]; gpc1 = grads + cc[1];
        gpc2 = grads + cc[2]; gpc3 = grads + cc[3];
        opc0 = out + cc[0]; opc1 = out + cc[1];
        opc2 = out + cc[2]; opc3 = out + cc[3];
        gp = nullptr; op = nullptr;
    }

    // scaled cell state (cS = 2log2e * c) and step-start B fragments
    float cS[5][4];
    #pragma unroll
    for (int t5 = 0; t5 < 5; ++t5)
        #pragma unroll
        for (int b = 0; b < 4; ++b) cS[t5][b] = 0.0f;

    bf16x8 B[4];
    {
        float x0[4];
        if constexpr (ALIGNED) {
            x0[0] = gp[0]; x0[1] = gp[16]; x0[2] = gp[32]; x0[3] = gp[48];
            gp += N;
        } else {
            x0[0] = *gpc0; gpc0 += N;
            x0[1] = *gpc1; gpc1 += N;
            x0[2] = *gpc2; gpc2 += N;
            x0[3] = *gpc3; gpc3 += N;
        }
        const float hz[5] = {0.0f, 0.0f, 0.0f, 0.0f, 0.0f};
        #pragma unroll
        for (int b = 0; b < 4; ++b)
            B[b] = build_frag(hz, fmaf(xm, x0[b], om));   // [h(-1)=0; x(0); 1]
    }

    #pragma unroll 1
    for (int t = 0; t < TT; ++t) {
        // prefetch x(t+1); last iter feeds 0 (pad slot, A column is zero)
        float xn[4];
        if (t + 1 < TT) {
            if constexpr (ALIGNED) {
                xn[0] = gp[0]; xn[1] = gp[16]; xn[2] = gp[32]; xn[3] = gp[48];
                gp += N;
            } else {
                xn[0] = *gpc0; gpc0 += N;
                xn[1] = *gpc1; gpc1 += N;
                xn[2] = *gpc2; gpc2 += N;
                xn[3] = *gpc3; gpc3 += N;
            }
        } else {
            xn[0] = 0.0f; xn[1] = 0.0f; xn[2] = 0.0f; xn[3] = 0.0f;
        }

        // per column-block b: 5 gate MFMAs -> 5 nonlins -> rebuild B[b] ->
        // out-projection MFMA -> store. hn live range = 5 regs.
        #pragma unroll
        for (int b = 0; b < 4; ++b) {
            f32x4 a0 = __builtin_amdgcn_mfma_f32_16x16x32_bf16(Ahi[0], B[b], zero4, 0, 0, 0);
            f32x4 a1 = __builtin_amdgcn_mfma_f32_16x16x32_bf16(Ahi[1], B[b], zero4, 0, 0, 0);
            f32x4 a2 = __builtin_amdgcn_mfma_f32_16x16x32_bf16(Ahi[2], B[b], zero4, 0, 0, 0);
            f32x4 a3 = __builtin_amdgcn_mfma_f32_16x16x32_bf16(Ahi[3], B[b], zero4, 0, 0, 0);
            f32x4 a4 = __builtin_amdgcn_mfma_f32_16x16x32_bf16(Ahi[4], B[b], zero4, 0, 0, 0);

            float hb[5];
            nonlin(a0, cS[0][b], hb[0]);
            nonlin(a1, cS[1][b], hb[1]);
            nonlin(a2, cS[2][b], hb[2]);
            nonlin(a3, cS[3][b], hb[3]);
            nonlin(a4, cS[4][b], hb[4]);

            B[b] = build_frag(hb, fmaf(xm, xn[b], om));   // [h(t); x(t+1); 1]

            f32x4 ov = __builtin_amdgcn_mfma_f32_16x16x32_bf16(Ahi[5], B[b], zero4, 0, 0, 0);
            if constexpr (ALIGNED) {
                if (g == 0) op[16 * b] = ov[0];
            } else {
                if (g == 0 && wr[b]) {
                    float* o = (b == 0) ? opc0 : (b == 1) ? opc1 : (b == 2) ? opc2 : opc3;
                    *o = ov[0];
                }
            }
        }

        if constexpr (ALIGNED) {
            op += N;
        } else {
            opc0 += N; opc1 += N; opc2 += N; opc3 += N;
        }
    }
}

extern "C" void kernel_launch(void* const* d_in, const int* in_sizes, int n_in,
                              void* d_out, int out_size, void* d_ws, size_t ws_size,
                              hipStream_t stream) {
    const float* grads = (const float*)d_in[0];
    const float* w_ih  = (const float*)d_in[1];
    const float* w_hh  = (const float*)d_in[2];
    const float* b_ih  = (const float*)d_in[3];
    const float* b_hh  = (const float*)d_in[4];
    const float* w_fc  = (const float*)d_in[5];
    const float* b_fc  = (const float*)d_in[6];
    float* out = (float*)d_out;

    const int N = in_sizes[0] / TT;            // grads is (T, N)
    const long long waves = ((long long)N + 63) / 64;
    const int blocks = (int)((waves + 3) / 4); // 4 waves per 256-thread block
    if (N % 64 == 0) {
        coord_lstm_mfma<true><<<blocks, 256, 0, stream>>>(grads, w_ih, w_hh, b_ih, b_hh,
                                                          w_fc, b_fc, out, N);
    } else {
        coord_lstm_mfma<false><<<blocks, 256, 0, stream>>>(grads, w_ih, w_hh, b_ih, b_hh,
                                                           w_fc, b_fc, out, N);
    }
}

// Round 13
// 350.264 us; speedup vs baseline: 1.7268x; 1.0324x over previous
//
#include <hip/hip_runtime.h>

#define TT 20
#define HH 20
#define NFRAG 2   // B-fragments (16 coords each) per wave: 32 coords/wave.
                  // Halves per-wave state vs 4-frag -> ~5 waves/SIMD resident
                  // to hide exp->rcp->fma chain latency. Total issue conserved.

typedef float f32x4 __attribute__((ext_vector_type(4)));
typedef float f32x2 __attribute__((ext_vector_type(2)));
typedef short bf16x8 __attribute__((ext_vector_type(8)));
typedef unsigned uint4v __attribute__((ext_vector_type(4)));

__device__ __forceinline__ short f2bf(float f) {
    unsigned u = __float_as_uint(f);
    unsigned r = (u + 0x7fffu + ((u >> 16) & 1u)) >> 16;
    return (short)r;
}

// packed f32x2 -> bf16x2 (RTNE), a -> low half, b -> high half
__device__ __forceinline__ unsigned pk_bf16(float a, float b) {
    unsigned r;
    asm("v_cvt_pk_bf16_f32 %0, %1, %2" : "=v"(r) : "v"(a), "v"(b));
    return r;
}

// One B fragment (pure bf16) from 5 lane-local h values + the e7 slot.
// Lane (g,n): B[k=8g+e][col]; e<5 -> h[unit 4e+g], e=7 -> x/1/0, e=5,6 pad.
__device__ __forceinline__ bf16x8 build_frag(const float (&h)[5], float s7) {
    uint4v uh;
    uh[0] = pk_bf16(h[0], h[1]);
    uh[1] = pk_bf16(h[2], h[3]);
    uh[2] = pk_bf16(h[4], 0.0f);
    uh[3] = pk_bf16(0.0f, s7);
    return __builtin_bit_cast(bf16x8, uh);
}

#define TLOG2E_C 2.8853900817779268f

// Per-unit nonlinearity. acc = (i',f',g',o'): i/f/o pre-scaled by -log2e,
// g by +2log2e at A-build. c-state stored PRE-SCALED by 2log2e (cS) so the
// tanh(c) exp needs no argument mul. 5 exp + 2 rcp per unit (trans floor).
__device__ __forceinline__ void nonlin(const f32x4 a, float& cS, float& hout) {
    f32x2 e_if, e_go;
    e_if.x = __builtin_amdgcn_exp2f(a[0]);
    e_if.y = __builtin_amdgcn_exp2f(a[1]);
    e_go.x = __builtin_amdgcn_exp2f(a[2]);
    e_go.y = __builtin_amdgcn_exp2f(a[3]);
    const f32x2 one2 = {1.0f, 1.0f};
    const f32x2 p_if = e_if + one2;          // v_pk_add_f32: (1+ei, 1+ef)
    const f32x2 p_go = e_go + one2;          // (1+eg, 1+eo)
    const float pig = p_if.x * p_go.x;
    const float r3  = __builtin_amdgcn_rcpf(pig * p_if.y);
    const float tn  = fmaf(e_go.x, TLOG2E_C, -TLOG2E_C) * p_if.y;  // 2log2e*(eg-1)*pf
    const float cnS = fmaf(cS, pig, tn) * r3;                      // = 2log2e * c_new
    cS = cnS;
    const float ec = __builtin_amdgcn_exp2f(cnS);
    const float pc = 1.0f + ec;
    hout = (ec - 1.0f) * __builtin_amdgcn_rcpf(p_go.y * pc);
}

// 256 threads = 4 independent waves; one wave = 32 coords, all 20 steps.
// Weights once in VGPR A-fragments; 12 MFMAs/step/wave. ALIGNED (N%32==0,
// true for the harness): one load + one store pointer, immediate offsets.
template <bool ALIGNED>
__global__ __launch_bounds__(256, 4)
void coord_lstm_mfma(const float* __restrict__ grads,
                     const float* __restrict__ w_ih,
                     const float* __restrict__ w_hh,
                     const float* __restrict__ b_ih,
                     const float* __restrict__ b_hh,
                     const float* __restrict__ w_fc,
                     const float* __restrict__ b_fc,
                     float* __restrict__ out,
                     int N)
{
    const int lane = threadIdx.x & 63;
    const int g = lane >> 4;
    const int n = lane & 15;
    const long long base =
        ((long long)blockIdx.x * 4 + (threadIdx.x >> 6)) * (16 * NFRAG);
    if (base >= N) return;

    const float LOG2E  = 1.4426950408889634f;
    const float TLOG2E = TLOG2E_C;
    const float xm = (g == 0) ? 1.0f : 0.0f;
    const float om = (g == 1) ? 1.0f : 0.0f;

    // ---- A fragments (bf16 RTNE), built once. Tiles 0..4: row r=16*tA+n ->
    // unit r>>2, gate r&3 (0=i 1=f 2=g 3=o), source row gate*HH+unit,
    // pre-scaled (-log2e for i/f/o, +2log2e for g). Tile 5: w_fc/b_fc.
    bf16x8 Ahi[6];
    #pragma unroll
    for (int tA = 0; tA < 6; ++tA) {
        bf16x8 ah;
        #pragma unroll
        for (int e = 0; e < 8; ++e) {
            float v = 0.0f;
            if (tA < 5) {
                const int r = 16 * tA + n;
                const int u_r = r >> 2;
                const int gate = r & 3;
                const float scale = (gate == 2) ? TLOG2E : -LOG2E;
                const int row_w = gate * HH + u_r;
                if (e < 5)       v = scale * w_hh[row_w * HH + (4 * e + g)];
                else if (e == 7) v = (g == 0) ? scale * w_ih[row_w]
                                   : (g == 1) ? scale * (b_ih[row_w] + b_hh[row_w]) : 0.0f;
            } else {
                if (e < 5)       v = (n == 0) ? w_fc[4 * e + g] : 0.0f;
                else if (e == 7) v = (g == 1 && n == 0) ? b_fc[0] : 0.0f;
            }
            ah[e] = f2bf(v);
        }
        Ahi[tA] = ah;
    }

    const f32x4 zero4 = {0.0f, 0.0f, 0.0f, 0.0f};

    // addressing
    const float* gp;
    float* op;
    long long cc[NFRAG]; bool wrk[NFRAG];
    const float* gpc[NFRAG];
    float* opc[NFRAG];
    if constexpr (ALIGNED) {
        gp = grads + base + n;
        op = out + base + n;
    } else {
        #pragma unroll
        for (int b = 0; b < NFRAG; ++b) {
            long long c0 = base + 16 * b + n;
            wrk[b] = (c0 < N);
            cc[b] = wrk[b] ? c0 : (long long)(N - 1);
            gpc[b] = grads + cc[b];
            opc[b] = out + cc[b];
        }
        gp = nullptr; op = nullptr;
    }

    // scaled cell state (cS = 2log2e * c) and step-start B fragments
    float cS[5][NFRAG];
    #pragma unroll
    for (int t5 = 0; t5 < 5; ++t5)
        #pragma unroll
        for (int b = 0; b < NFRAG; ++b) cS[t5][b] = 0.0f;

    bf16x8 B[NFRAG];
    {
        float x0[NFRAG];
        if constexpr (ALIGNED) {
            #pragma unroll
            for (int b = 0; b < NFRAG; ++b) x0[b] = gp[16 * b];
            gp += N;
        } else {
            #pragma unroll
            for (int b = 0; b < NFRAG; ++b) { x0[b] = *gpc[b]; gpc[b] += N; }
        }
        const float hz[5] = {0.0f, 0.0f, 0.0f, 0.0f, 0.0f};
        #pragma unroll
        for (int b = 0; b < NFRAG; ++b)
            B[b] = build_frag(hz, fmaf(xm, x0[b], om));   // [h(-1)=0; x(0); 1]
    }

    #pragma unroll 1
    for (int t = 0; t < TT; ++t) {
        // prefetch x(t+1); last iter feeds 0 (pad slot, A column is zero)
        float xn[NFRAG];
        if (t + 1 < TT) {
            if constexpr (ALIGNED) {
                #pragma unroll
                for (int b = 0; b < NFRAG; ++b) xn[b] = gp[16 * b];
                gp += N;
            } else {
                #pragma unroll
                for (int b = 0; b < NFRAG; ++b) { xn[b] = *gpc[b]; gpc[b] += N; }
            }
        } else {
            #pragma unroll
            for (int b = 0; b < NFRAG; ++b) xn[b] = 0.0f;
        }

        // per column-block b: 5 gate MFMAs -> 5 nonlins -> rebuild B[b] ->
        // out-projection MFMA -> store. hn live range = 5 regs.
        #pragma unroll
        for (int b = 0; b < NFRAG; ++b) {
            f32x4 a0 = __builtin_amdgcn_mfma_f32_16x16x32_bf16(Ahi[0], B[b], zero4, 0, 0, 0);
            f32x4 a1 = __builtin_amdgcn_mfma_f32_16x16x32_bf16(Ahi[1], B[b], zero4, 0, 0, 0);
            f32x4 a2 = __builtin_amdgcn_mfma_f32_16x16x32_bf16(Ahi[2], B[b], zero4, 0, 0, 0);
            f32x4 a3 = __builtin_amdgcn_mfma_f32_16x16x32_bf16(Ahi[3], B[b], zero4, 0, 0, 0);
            f32x4 a4 = __builtin_amdgcn_mfma_f32_16x16x32_bf16(Ahi[4], B[b], zero4, 0, 0, 0);

            float hb[5];
            nonlin(a0, cS[0][b], hb[0]);
            nonlin(a1, cS[1][b], hb[1]);
            nonlin(a2, cS[2][b], hb[2]);
            nonlin(a3, cS[3][b], hb[3]);
            nonlin(a4, cS[4][b], hb[4]);

            B[b] = build_frag(hb, fmaf(xm, xn[b], om));   // [h(t); x(t+1); 1]

            f32x4 ov = __builtin_amdgcn_mfma_f32_16x16x32_bf16(Ahi[5], B[b], zero4, 0, 0, 0);
            if constexpr (ALIGNED) {
                if (g == 0) op[16 * b] = ov[0];
            } else {
                if (g == 0 && wrk[b]) *opc[b] = ov[0];
            }
        }

        if constexpr (ALIGNED) {
            op += N;
        } else {
            #pragma unroll
            for (int b = 0; b < NFRAG; ++b) opc[b] += N;
        }
    }
}

extern "C" void kernel_launch(void* const* d_in, const int* in_sizes, int n_in,
                              void* d_out, int out_size, void* d_ws, size_t ws_size,
                              hipStream_t stream) {
    const float* grads = (const float*)d_in[0];
    const float* w_ih  = (const float*)d_in[1];
    const float* w_hh  = (const float*)d_in[2];
    const float* b_ih  = (const float*)d_in[3];
    const float* b_hh  = (const float*)d_in[4];
    const float* w_fc  = (const float*)d_in[5];
    const float* b_fc  = (const float*)d_in[6];
    float* out = (float*)d_out;

    const int N = in_sizes[0] / TT;              // grads is (T, N)
    const int cpw = 16 * NFRAG;                  // coords per wave
    const long long waves = ((long long)N + cpw - 1) / cpw;
    const int blocks = (int)((waves + 3) / 4);   // 4 waves per 256-thread block
    if (N % cpw == 0) {
        coord_lstm_mfma<true><<<blocks, 256, 0, stream>>>(grads, w_ih, w_hh, b_ih, b_hh,
                                                          w_fc, b_fc, out, N);
    } else {
        coord_lstm_mfma<false><<<blocks, 256, 0, stream>>>(grads, w_ih, w_hh, b_ih, b_hh,
                                                           w_fc, b_fc, out, N);
    }
}